// Round 20
// baseline (247.503 us; speedup 1.0000x reference)
//
#include <hip/hip_runtime.h>

typedef __bf16 bf16x8 __attribute__((ext_vector_type(8)));
typedef float f32x4 __attribute__((ext_vector_type(4)));

#define PI_F 3.14159265358979323846f

__device__ __forceinline__ unsigned short f2bf(float f) {
  unsigned u = __builtin_bit_cast(unsigned, f);
  u += 0x7fffu + ((u >> 16) & 1u);
  return (unsigned short)(u >> 16);
}

__device__ __forceinline__ unsigned scale_pair(unsigned w, float f) {
  const float lo = __builtin_bit_cast(float, w << 16);
  const float hi = __builtin_bit_cast(float, w & 0xffff0000u);
  return (unsigned)f2bf(lo * f) | ((unsigned)f2bf(hi * f) << 16);
}

#define GLD16(gp, lp)                                          \
  __builtin_amdgcn_global_load_lds(                            \
      (const __attribute__((address_space(1))) void*)(gp),     \
      (__attribute__((address_space(3))) void*)(lp), 16, 0, 0)

struct AReg { float4 a0, a1, a2, a3, a4, a5, a6, a7; };

__device__ __forceinline__ uint4 cvtpk16(float4 x, float4 y) {
  unsigned c0, c1, c2, c3;
  asm("v_cvt_pk_bf16_f32 %0, %1, %2" : "=v"(c0) : "v"(x.x), "v"(x.y));
  asm("v_cvt_pk_bf16_f32 %0, %1, %2" : "=v"(c1) : "v"(x.z), "v"(x.w));
  asm("v_cvt_pk_bf16_f32 %0, %1, %2" : "=v"(c2) : "v"(y.x), "v"(y.y));
  asm("v_cvt_pk_bf16_f32 %0, %1, %2" : "=v"(c3) : "v"(y.z), "v"(y.w));
  uint4 u; u.x = c0; u.y = c1; u.z = c2; u.w = c3;
  return u;
}

__device__ __forceinline__ uint2 cvtpk8(float a, float b, float c, float d) {
  unsigned lo, hi;
  asm("v_cvt_pk_bf16_f32 %0, %1, %2" : "=v"(lo) : "v"(a), "v"(b));
  asm("v_cvt_pk_bf16_f32 %0, %1, %2" : "=v"(hi) : "v"(c), "v"(d));
  uint2 r; r.x = lo; r.y = hi;
  return r;
}

__device__ __forceinline__ void unpack8(uint4 w, float* f) {
  f[0] = __builtin_bit_cast(float, w.x << 16);
  f[1] = __builtin_bit_cast(float, w.x & 0xffff0000u);
  f[2] = __builtin_bit_cast(float, w.y << 16);
  f[3] = __builtin_bit_cast(float, w.y & 0xffff0000u);
  f[4] = __builtin_bit_cast(float, w.z << 16);
  f[5] = __builtin_bit_cast(float, w.z & 0xffff0000u);
  f[6] = __builtin_bit_cast(float, w.w << 16);
  f[7] = __builtin_bit_cast(float, w.w & 0xffff0000u);
}

// ---------------- k1: weight fp32 -> bf16 conversion (weights only) ----------------
__global__ __launch_bounds__(256) void convert_w(
    const float* __restrict__ Wq, const float* __restrict__ Wk,
    const float* __restrict__ Wv, const float* __restrict__ Wo,
    unsigned short* __restrict__ Wqb, unsigned short* __restrict__ Wkb,
    unsigned short* __restrict__ Wvb, unsigned short* __restrict__ Wob) {
  const int region = blockIdx.y;
  const float* s; unsigned short* d;
  switch (region) {
    case 0: s = Wq; d = Wqb; break;
    case 1: s = Wk; d = Wkb; break;
    case 2: s = Wv; d = Wvb; break;
    default: s = Wo; d = Wob; break;
  }
  const float4* s4 = (const float4*)s;
  ushort4* d4 = (ushort4*)d;
  const int n4 = 262144;
  for (int i = blockIdx.x * 256 + threadIdx.x; i < n4; i += gridDim.x * 256) {
    float4 f = s4[i];
    ushort4 o;
    o.x = f2bf(f.x); o.y = f2bf(f.y); o.z = f2bf(f.z); o.w = f2bf(f.w);
    d4[i] = o;
  }
}

// ---------------- fused Q/K/V: 256x256 bf16 GEMM, 4-phase read-once pipeline -------
// grid 768: seg = bid>>8 (0:Q relu->permuted Qh; 1:K relu->Kt; 2:V->Vt).
// LDS 160KB (A 2 bufs @0, B 3 bufs @32768), B staged 2 tiles ahead, single AReg.
// Per K-tile: 4 phases split by (M-half, K-half); B frags of a K-half read once
// in ph0/ph2 and held for 2 phases (24 ds_read_b128/tile total). Each phase:
// issue reads/stage -> barrier -> lgkmcnt(0)+sched_barrier -> 16-MFMA cluster
// (setprio-wrapped) -> barrier. AWRITE(kt+1) in ph2 carries the implicit counted
// vmcnt on R, which transitively guarantees B(kt+1) landed (B issued before A).
__global__ __launch_bounds__(512, 2) void gemm_qkv(
    const float* __restrict__ q, const float* __restrict__ k, const float* __restrict__ v,
    const unsigned short* __restrict__ Wqb, const unsigned short* __restrict__ Wkb,
    const unsigned short* __restrict__ Wvb,
    const float* __restrict__ bq, const float* __restrict__ bk, const float* __restrict__ bv,
    unsigned short* __restrict__ Qh, unsigned short* __restrict__ Kt,
    unsigned short* __restrict__ Vt) {
  constexpr int K = 1024, NKT = 16;
  __shared__ unsigned short S[81920];
  const int seg = blockIdx.x >> 8;
  const int bid2 = blockIdx.x & 255;
  const float* A32 = seg == 0 ? q : (seg == 1 ? k : v);
  const unsigned short* Bw = seg == 0 ? Wqb : (seg == 1 ? Wkb : Wvb);
  const float* bias = seg == 0 ? bq : (seg == 1 ? bk : bv);

  const int tid = threadIdx.x;
  const int wave = tid >> 6, lane = tid & 63;
  const int fr = lane & 15, fq = lane >> 4;
  const int wr = wave >> 2, wc = wave & 3;
  const int wg = (bid2 & 7) * 32 + (bid2 >> 3);
  const int mt = wg >> 2, ntile = wg & 3;
  const int m0 = mt * 256, n0 = ntile * 256;

  const int srow = tid >> 3;
  const int ac16 = tid & 7;
  const int scolE = ((ac16 << 4) ^ ((srow & 7) << 4)) >> 1;  // pre-swizzled src col (elems)
  const unsigned short* bSrc = Bw + (size_t)(n0 + srow) * K + scolE;
  const int awoff = (ac16 ^ (srow & 7)) << 3;  // swizzled dst chunk (elems)
  AReg R;

#define BSTAGE(kt_, idx_) do {                                                     \
    const int kc_ = (kt_) * 64;                                                    \
    unsigned short* bb_ = S + 32768 + (idx_) * 16384 + wave * 512;                 \
    GLD16(bSrc + kc_, bb_);                                                        \
    GLD16(bSrc + (size_t)65536 + kc_, bb_ + 4096);                                 \
    GLD16(bSrc + (size_t)131072 + kc_, bb_ + 8192);                                \
    GLD16(bSrc + (size_t)196608 + kc_, bb_ + 12288);                               \
  } while (0)

#define ALOAD_ALL(kt_) do {                                                        \
    const int kc_ = (kt_) * 64;                                                    \
    const float4* p_;                                                              \
    p_ = (const float4*)(A32 + (size_t)(m0 + srow) * K + kc_) + ac16 * 2;          \
    R.a0 = p_[0]; R.a1 = p_[1];                                                    \
    p_ = (const float4*)(A32 + (size_t)(m0 + 64 + srow) * K + kc_) + ac16 * 2;     \
    R.a2 = p_[0]; R.a3 = p_[1];                                                    \
    p_ = (const float4*)(A32 + (size_t)(m0 + 128 + srow) * K + kc_) + ac16 * 2;    \
    R.a4 = p_[0]; R.a5 = p_[1];                                                    \
    p_ = (const float4*)(A32 + (size_t)(m0 + 192 + srow) * K + kc_) + ac16 * 2;    \
    R.a6 = p_[0]; R.a7 = p_[1];                                                    \
  } while (0)

#define AWRITE_ALL(idx_) do {                                                      \
    unsigned short* dst_ = &S[(idx_) * 16384 + srow * 64 + awoff];                 \
    *(uint4*)(dst_)         = cvtpk16(R.a0, R.a1);                                 \
    *(uint4*)(dst_ + 4096)  = cvtpk16(R.a2, R.a3);                                 \
    *(uint4*)(dst_ + 8192)  = cvtpk16(R.a4, R.a5);                                 \
    *(uint4*)(dst_ + 12288) = cvtpk16(R.a6, R.a7);                                 \
  } while (0)

  const int xorv = (fr & 7) << 4;
  const unsigned cbE0 = (unsigned)(((fq * 16) ^ xorv) >> 1);
  const unsigned cbE1 = (unsigned)(((64 + fq * 16) ^ xorv) >> 1);

  f32x4 acc[8][4] = {};
  ALOAD_ALL(0);
  BSTAGE(0, 0);
  BSTAGE(1, 1);
  AWRITE_ALL(0);
  ALOAD_ALL(1);
  asm volatile("s_waitcnt vmcnt(12) lgkmcnt(0)" ::: "memory");
  __builtin_amdgcn_s_barrier();

  for (int kt = 0; kt < NKT; ++kt) {
    const unsigned aB = (unsigned)((kt & 1) * 16384 + wr * 8192 + fr * 64);
    int bcur = kt % 3;
    const unsigned bB = (unsigned)(32768 + bcur * 16384 + (wc >> 1) * 8192 +
                                   ((wc & 1) * 64 + fr) * 64);
    bf16x8 av[4], bv[4];
    // ======== ph0: (m0-3, kh0); stage B(kt+2) ========
#pragma unroll
    for (int nn = 0; nn < 4; ++nn)
      bv[nn] = *(const bf16x8*)&S[bB + (unsigned)(nn * 1024) + cbE0];
#pragma unroll
    for (int mm = 0; mm < 4; ++mm)
      av[mm] = *(const bf16x8*)&S[aB + (unsigned)(mm * 1024) + cbE0];
    if (kt + 2 < NKT) {
      int bst = bcur + 2; if (bst >= 3) bst -= 3;
      BSTAGE(kt + 2, bst);
    }
    __builtin_amdgcn_s_barrier();
    asm volatile("s_waitcnt lgkmcnt(0)" ::: "memory");
    __builtin_amdgcn_sched_barrier(0);
    __builtin_amdgcn_s_setprio(1);
#pragma unroll
    for (int mm = 0; mm < 4; ++mm)
#pragma unroll
      for (int nn = 0; nn < 4; ++nn)
        acc[mm][nn] = __builtin_amdgcn_mfma_f32_16x16x32_bf16(av[mm], bv[nn], acc[mm][nn], 0, 0, 0);
    __builtin_amdgcn_s_setprio(0);
    __builtin_amdgcn_s_barrier();
    // ======== ph1: (m4-7, kh0); B held ========
#pragma unroll
    for (int mm = 0; mm < 4; ++mm)
      av[mm] = *(const bf16x8*)&S[aB + (unsigned)((4 + mm) * 1024) + cbE0];
    __builtin_amdgcn_s_barrier();
    asm volatile("s_waitcnt lgkmcnt(0)" ::: "memory");
    __builtin_amdgcn_sched_barrier(0);
    __builtin_amdgcn_s_setprio(1);
#pragma unroll
    for (int mm = 0; mm < 4; ++mm)
#pragma unroll
      for (int nn = 0; nn < 4; ++nn)
        acc[4 + mm][nn] = __builtin_amdgcn_mfma_f32_16x16x32_bf16(av[mm], bv[nn], acc[4 + mm][nn], 0, 0, 0);
    __builtin_amdgcn_s_setprio(0);
    __builtin_amdgcn_s_barrier();
    // ======== ph2: (m0-3, kh1); AWRITE(kt+1) (counted vmcnt on R) ========
#pragma unroll
    for (int nn = 0; nn < 4; ++nn)
      bv[nn] = *(const bf16x8*)&S[bB + (unsigned)(nn * 1024) + cbE1];
#pragma unroll
    for (int mm = 0; mm < 4; ++mm)
      av[mm] = *(const bf16x8*)&S[aB + (unsigned)(mm * 1024) + cbE1];
    if (kt + 1 < NKT) AWRITE_ALL((kt + 1) & 1);
    __builtin_amdgcn_s_barrier();
    asm volatile("s_waitcnt lgkmcnt(0)" ::: "memory");
    __builtin_amdgcn_sched_barrier(0);
    __builtin_amdgcn_s_setprio(1);
#pragma unroll
    for (int mm = 0; mm < 4; ++mm)
#pragma unroll
      for (int nn = 0; nn < 4; ++nn)
        acc[mm][nn] = __builtin_amdgcn_mfma_f32_16x16x32_bf16(av[mm], bv[nn], acc[mm][nn], 0, 0, 0);
    __builtin_amdgcn_s_setprio(0);
    __builtin_amdgcn_s_barrier();
    // ======== ph3: (m4-7, kh1); ALOAD(kt+2) ========
#pragma unroll
    for (int mm = 0; mm < 4; ++mm)
      av[mm] = *(const bf16x8*)&S[aB + (unsigned)((4 + mm) * 1024) + cbE1];
    if (kt + 2 < NKT) ALOAD_ALL(kt + 2);
    __builtin_amdgcn_s_barrier();
    asm volatile("s_waitcnt lgkmcnt(0)" ::: "memory");
    __builtin_amdgcn_sched_barrier(0);
    __builtin_amdgcn_s_setprio(1);
#pragma unroll
    for (int mm = 0; mm < 4; ++mm)
#pragma unroll
      for (int nn = 0; nn < 4; ++nn)
        acc[4 + mm][nn] = __builtin_amdgcn_mfma_f32_16x16x32_bf16(av[mm], bv[nn], acc[4 + mm][nn], 0, 0, 0);
    __builtin_amdgcn_s_setprio(0);
    __builtin_amdgcn_s_barrier();
  }
#undef BSTAGE
#undef ALOAD_ALL
#undef AWRITE_ALL

  const int colb = n0 + wc * 64 + fr;
  const int rtb0 = wr * 128 + fq * 4;
  const int mlo = m0 & 4095;
  const int b16 = (m0 >> 12) << 4;
  const int hbase = n0 >> 6;

  if (seg == 0) {
    // Q: relu -> LDS row-major [rt:256][ct:256] (16B-chunk swizzled) -> 128B runs
    float bb4[4];
#pragma unroll
    for (int nq = 0; nq < 4; ++nq) bb4[nq] = bias[colb + nq * 16];
    __syncthreads();
#pragma unroll
    for (int mq = 0; mq < 8; ++mq) {
#pragma unroll
      for (int rr = 0; rr < 4; ++rr) {
        const int rt = rtb0 + mq * 16 + rr;
        const int e = (rt >> 2) & 7;
#pragma unroll
        for (int nq = 0; nq < 4; ++nq) {
          const int ct = wc * 64 + nq * 16 + fr;
          const int sct = (ct & 7) | ((((ct >> 3) ^ e) & 31) << 3);
          S[rt * 256 + sct] = f2bf(fmaxf(acc[mq][nq][rr] + bb4[nq], 0.0f));
        }
      }
    }
    __syncthreads();
#pragma unroll
    for (int it = 0; it < 16; ++it) {
      const int rt = it * 16 + (tid >> 5);
      const int co = tid & 31;
      const int chunk = co ^ ((rt >> 2) & 7);
      uint4 w = *(const uint4*)&S[rt * 256 + chunk * 8];
      const int h = hbase + (co >> 3);
      const size_t addr = ((size_t)(b16 + h) * 4096 + mlo + rt) * 64 + ((co & 7) << 3);
      *(uint4*)(Qh + addr) = w;
    }
  } else {
    // K/V: transposed [bh][64][4096] bf16 via LDS col-major transpose; relu iff K
    const bool relu = (seg == 1);
    unsigned short* G = relu ? Kt : Vt;
    float bb4[4];
#pragma unroll
    for (int nq = 0; nq < 4; ++nq) bb4[nq] = bias[colb + nq * 16];
#pragma unroll
    for (int mq = 0; mq < 8; ++mq)
#pragma unroll
      for (int nq = 0; nq < 4; ++nq)
#pragma unroll
        for (int rr = 0; rr < 4; ++rr) {
          float val = acc[mq][nq][rr] + bb4[nq];
          if (relu) val = fmaxf(val, 0.0f);
          acc[mq][nq][rr] = val;
        }
    __syncthreads();
#pragma unroll
    for (int mq = 0; mq < 8; ++mq) {
      const int rtb = rtb0 + mq * 16;
#pragma unroll
      for (int nq = 0; nq < 4; ++nq) {
        const int ct = wc * 64 + nq * 16 + fr;
        uint2 w = cvtpk8(acc[mq][nq][0], acc[mq][nq][1], acc[mq][nq][2], acc[mq][nq][3]);
        *(uint2*)&S[ct * 256 + (rtb ^ ((ct & 7) << 2))] = w;
      }
    }
    __syncthreads();
#pragma unroll
    for (int it = 0; it < 16; ++it) {
      const int ct = it * 16 + (tid >> 5);
      const int lo = (tid & 31) << 3;
      const int sw = (ct & 7) << 2;
      uint2 r0 = *(const uint2*)&S[ct * 256 + (lo ^ sw)];
      uint2 r1 = *(const uint2*)&S[ct * 256 + ((lo + 4) ^ sw)];
      uint4 w; w.x = r0.x; w.y = r0.y; w.z = r1.x; w.w = r1.y;
      const int h = hbase + (ct >> 6), dd = ct & 63;
      const size_t addr = ((size_t)(b16 + h) * 64 + dd) * 4096 + mlo + lo;
      *(uint4*)(G + addr) = w;
    }
  }
}

// ---------------- O projection: 1-barrier/K-tile, bf16 A, bf16 out ----------------
__global__ __launch_bounds__(512, 2) void gemm_o(
    const unsigned short* __restrict__ Ain, const unsigned short* __restrict__ Bw,
    const float* __restrict__ bias, unsigned short* __restrict__ out) {
  constexpr int K = 1024, NKT = 16;
  __shared__ unsigned short S[81920];  // A 2 bufs @0, B 3 bufs @32768
  const int tid = threadIdx.x;
  const int wave = tid >> 6, lane = tid & 63;
  const int fr = lane & 15, fq = lane >> 4;
  const int wr = wave >> 2, wc = wave & 3;
  const int wg = (blockIdx.x & 7) * 32 + (blockIdx.x >> 3);
  const int mt = wg >> 2, ntile = wg & 3;
  const int m0 = mt * 256, n0 = ntile * 256;

  const int srow = tid >> 3;
  const int ac16 = tid & 7;
  const int scolE = ((ac16 << 4) ^ ((srow & 7) << 4)) >> 1;
  const unsigned short* bSrc = Bw + (size_t)(n0 + srow) * K + scolE;
  const unsigned short* aSrcB = Ain + (size_t)(m0 + srow) * K + scolE;

#define BSTAGE(kt_, idx_) do {                                                     \
    const int kc_ = (kt_) * 64;                                                    \
    unsigned short* bb_ = S + 32768 + (idx_) * 16384 + wave * 512;                 \
    GLD16(bSrc + kc_, bb_);                                                        \
    GLD16(bSrc + (size_t)65536 + kc_, bb_ + 4096);                                 \
    GLD16(bSrc + (size_t)131072 + kc_, bb_ + 8192);                                \
    GLD16(bSrc + (size_t)196608 + kc_, bb_ + 12288);                               \
  } while (0)

#define ASTAGE(kt_, idx_) do {                                                     \
    const int kc_ = (kt_) * 64;                                                    \
    unsigned short* ab_ = S + (idx_) * 16384 + wave * 512;                         \
    GLD16(aSrcB + kc_, ab_);                                                       \
    GLD16(aSrcB + (size_t)65536 + kc_, ab_ + 4096);                                \
    GLD16(aSrcB + (size_t)131072 + kc_, ab_ + 8192);                               \
    GLD16(aSrcB + (size_t)196608 + kc_, ab_ + 12288);                              \
  } while (0)

  const int xorv = (fr & 7) << 4;
  const unsigned cbE0 = (unsigned)(((fq * 16) ^ xorv) >> 1);
  const unsigned cbE1 = (unsigned)(((64 + fq * 16) ^ xorv) >> 1);

  f32x4 acc[8][4] = {};
  ASTAGE(0, 0);
  BSTAGE(0, 0);
  BSTAGE(1, 1);
  asm volatile("s_waitcnt vmcnt(4)" ::: "memory");
  __builtin_amdgcn_s_barrier();

  int bcur = 0;
  for (int kt = 0; kt < NKT; ++kt) {
    const unsigned aB = (unsigned)((kt & 1) * 16384 + wr * 8192 + fr * 64);
    const unsigned bB = (unsigned)(32768 + bcur * 16384 + (wc >> 1) * 8192 +
                                   ((wc & 1) * 64 + fr) * 64);
    if (kt + 2 < NKT) {
      int bst = bcur + 2; if (bst >= 3) bst -= 3;
      BSTAGE(kt + 2, bst);
    }
    if (kt + 1 < NKT) ASTAGE(kt + 1, (kt + 1) & 1);
    bf16x8 af[4][2], b0[2][2], b1[2][2];
#pragma unroll
    for (int mm = 0; mm < 4; ++mm) {
      const unsigned r = aB + (unsigned)(mm * 1024);
      af[mm][0] = *(const bf16x8*)&S[r + cbE0];
      af[mm][1] = *(const bf16x8*)&S[r + cbE1];
    }
#pragma unroll
    for (int nn = 0; nn < 2; ++nn) {
      const unsigned r0 = bB + (unsigned)(nn * 1024);
      b0[nn][0] = *(const bf16x8*)&S[r0 + cbE0];
      b0[nn][1] = *(const bf16x8*)&S[r0 + cbE1];
      const unsigned r1 = bB + (unsigned)((2 + nn) * 1024);
      b1[nn][0] = *(const bf16x8*)&S[r1 + cbE0];
      b1[nn][1] = *(const bf16x8*)&S[r1 + cbE1];
    }
    __builtin_amdgcn_s_setprio(1);
#pragma unroll
    for (int mm = 0; mm < 4; ++mm) {
#pragma unroll
      for (int nn = 0; nn < 2; ++nn) {
        acc[mm][nn] = __builtin_amdgcn_mfma_f32_16x16x32_bf16(af[mm][0], b0[nn][0], acc[mm][nn], 0, 0, 0);
        acc[mm][nn] = __builtin_amdgcn_mfma_f32_16x16x32_bf16(af[mm][1], b0[nn][1], acc[mm][nn], 0, 0, 0);
        acc[mm][2 + nn] = __builtin_amdgcn_mfma_f32_16x16x32_bf16(af[mm][0], b1[nn][0], acc[mm][2 + nn], 0, 0, 0);
        acc[mm][2 + nn] = __builtin_amdgcn_mfma_f32_16x16x32_bf16(af[mm][1], b1[nn][1], acc[mm][2 + nn], 0, 0, 0);
      }
    }
    __builtin_amdgcn_s_setprio(0);
#pragma unroll
    for (int mm = 0; mm < 4; ++mm) {
      const unsigned r = aB + (unsigned)((4 + mm) * 1024);
      af[mm][0] = *(const bf16x8*)&S[r + cbE0];
      af[mm][1] = *(const bf16x8*)&S[r + cbE1];
    }
    __builtin_amdgcn_s_setprio(1);
#pragma unroll
    for (int mm = 0; mm < 4; ++mm) {
#pragma unroll
      for (int nn = 0; nn < 2; ++nn) {
        acc[4 + mm][nn] = __builtin_amdgcn_mfma_f32_16x16x32_bf16(af[mm][0], b0[nn][0], acc[4 + mm][nn], 0, 0, 0);
        acc[4 + mm][nn] = __builtin_amdgcn_mfma_f32_16x16x32_bf16(af[mm][1], b0[nn][1], acc[4 + mm][nn], 0, 0, 0);
        acc[4 + mm][2 + nn] = __builtin_amdgcn_mfma_f32_16x16x32_bf16(af[mm][0], b1[nn][0], acc[4 + mm][2 + nn], 0, 0, 0);
        acc[4 + mm][2 + nn] = __builtin_amdgcn_mfma_f32_16x16x32_bf16(af[mm][1], b1[nn][1], acc[4 + mm][2 + nn], 0, 0, 0);
      }
    }
    __builtin_amdgcn_s_setprio(0);
    // counted wait: A(kt+1), B(kt+1) landed; only B(kt+2)'s 4 loads newer
    if (kt + 2 < NKT) {
      asm volatile("s_waitcnt vmcnt(4) lgkmcnt(0)" ::: "memory");
    } else if (kt + 1 < NKT) {
      asm volatile("s_waitcnt vmcnt(0) lgkmcnt(0)" ::: "memory");
    } else {
      asm volatile("s_waitcnt lgkmcnt(0)" ::: "memory");
    }
    __builtin_amdgcn_s_barrier();
    bcur = bcur + 1; if (bcur == 3) bcur = 0;
  }
#undef BSTAGE
#undef ASTAGE

  // bf16 row-major out via 4-pass LDS row gather; 512B runs per wave-store.
  const int colb = n0 + wc * 64 + fr;
  float* Sf = (float*)S;  // 64 rows x 260 f32
  float bb4[4];
#pragma unroll
  for (int nq = 0; nq < 4; ++nq) bb4[nq] = bias[colb + nq * 16];
  const int colL = wc * 64;
#pragma unroll
  for (int h4 = 0; h4 < 4; ++h4) {
    __syncthreads();
    if (wr == (h4 >> 1)) {
      const int mqb = (h4 & 1) * 4;
#pragma unroll
      for (int mq2 = 0; mq2 < 4; ++mq2) {
        const int rl = mq2 * 16 + fq * 4;
#pragma unroll
        for (int nq = 0; nq < 4; ++nq) {
#pragma unroll
          for (int rr = 0; rr < 4; ++rr)
            Sf[(rl + rr) * 260 + colL + nq * 16 + fr] = acc[mqb + mq2][nq][rr] + bb4[nq];
        }
      }
    }
    __syncthreads();
#pragma unroll
    for (int i = 0; i < 8; ++i) {
      const int rl = wave * 8 + i;
      const int gr = m0 + h4 * 64 + rl;
      f32x4 v4 = *(const f32x4*)&Sf[rl * 260 + lane * 4];
      uint2 w = cvtpk8(v4.x, v4.y, v4.z, v4.w);
      *(uint2*)(out + (size_t)gr * 1024 + n0 + lane * 4) = w;
    }
  }
}

// ---------------- expand: bf16 [16384][1024] -> fp32 d_out (fully coalesced) ------
__global__ __launch_bounds__(256) void expand_bf16_f32(
    const unsigned short* __restrict__ in, float* __restrict__ out) {
  const int stride = gridDim.x * 256;
  for (int i = blockIdx.x * 256 + threadIdx.x; i < 4194304; i += stride) {
    uint2 w = ((const uint2*)in)[i];
    f32x4 o;
    o.x = __builtin_bit_cast(float, w.x << 16);
    o.y = __builtin_bit_cast(float, w.x & 0xffff0000u);
    o.z = __builtin_bit_cast(float, w.y << 16);
    o.w = __builtin_bit_cast(float, w.y & 0xffff0000u);
    ((f32x4*)out)[i] = o;
  }
}

// ---------------- k3: kv partial GEMM via MFMA, sin/cos expansion in-kernel ----------------
__global__ __launch_bounds__(256, 2) void kv_gemm(
    const unsigned short* __restrict__ Vt,   // [64][64][4096]
    const unsigned short* __restrict__ Kt,   // [64][64][4096], relu'd
    float* __restrict__ kvp) {               // [64*8][65][128]
  __shared__ unsigned short As[64 * 64];
  __shared__ unsigned short Bs[128 * 64];
  __shared__ float sn[512], cn[512];
  const int tid = threadIdx.x, wave = tid >> 6, lane = tid & 63;
  const int fr = lane & 15, fq = lane >> 4;
  const int ls = blockIdx.x, bh = blockIdx.y;
  const size_t base = (size_t)bh * 64 * 4096;
  {
    float s0, c0, s1, c1;
    __sincosf(PI_F * (float)(ls * 512 + tid + 1) * (1.0f / 8192.0f), &s0, &c0);
    __sincosf(PI_F * (float)(ls * 512 + tid + 257) * (1.0f / 8192.0f), &s1, &c1);
    sn[tid] = s0; cn[tid] = c0;
    sn[tid + 256] = s1; cn[tid + 256] = c1;
  }
  f32x4 acc[5][2] = {};
  bf16x8 ones;
#pragma unroll
  for (int j = 0; j < 8; ++j) ones[j] = (__bf16)1.0f;
  for (int t = 0; t < 8; ++t) {
    const int l0 = ls * 512 + t * 64;
    __syncthreads();
#pragma unroll
    for (int j = 0; j < 2; ++j) {
      const int p = j * 256 + tid;
      const int row = p >> 3, cc = (p & 7) ^ (row & 7);
      GLD16(Vt + base + (size_t)row * 4096 + l0 + cc * 8,
            As + ((j << 8) + (wave << 6)) * 8);
    }
#pragma unroll
    for (int j = 0; j < 2; ++j) {
      const int p = j * 256 + tid;
      const int kr = p >> 3, cc = p & 7;
      const uint4 w = *(const uint4*)(Kt + base + (size_t)kr * 4096 + l0 + cc * 8);
      const int tl = t * 64 + cc * 8;
      float kf[8];
      unpack8(w, kf);
      const float4 sA = *(const float4*)&sn[tl], sB = *(const float4*)&sn[tl + 4];
      const float4 cA = *(const float4*)&cn[tl], cB = *(const float4*)&cn[tl + 4];
      float4 x0, x1;
      x0.x = kf[0] * sA.x; x0.y = kf[1] * sA.y; x0.z = kf[2] * sA.z; x0.w = kf[3] * sA.w;
      x1.x = kf[4] * sB.x; x1.y = kf[5] * sB.y; x1.z = kf[6] * sB.z; x1.w = kf[7] * sB.w;
      const uint4 wsn = cvtpk16(x0, x1);
      x0.x = kf[0] * cA.x; x0.y = kf[1] * cA.y; x0.z = kf[2] * cA.z; x0.w = kf[3] * cA.w;
      x1.x = kf[4] * cB.x; x1.y = kf[5] * cB.y; x1.z = kf[6] * cB.z; x1.w = kf[7] * cB.w;
      const uint4 wcn = cvtpk16(x0, x1);
      const int sw_ = cc ^ (kr & 7);
      *(uint4*)&Bs[(kr * 8 + sw_) * 8] = wsn;
      *(uint4*)&Bs[((kr + 64) * 8 + sw_) * 8] = wcn;
    }
    __syncthreads();
#pragma unroll
    for (int kk = 0; kk < 2; ++kk) {
      const int ch = kk * 4 + fq;
      bf16x8 a[4], b[2];
#pragma unroll
      for (int m = 0; m < 4; ++m) {
        const int r = m * 16 + fr;
        a[m] = *(const bf16x8*)&As[(r * 8 + (ch ^ (r & 7))) * 8];
      }
#pragma unroll
      for (int n = 0; n < 2; ++n) {
        const int r = wave * 32 + n * 16 + fr;
        b[n] = *(const bf16x8*)&Bs[(r * 8 + (ch ^ (r & 7))) * 8];
      }
#pragma unroll
      for (int m = 0; m < 4; ++m)
#pragma unroll
        for (int n = 0; n < 2; ++n)
          acc[m][n] = __builtin_amdgcn_mfma_f32_16x16x32_bf16(a[m], b[n], acc[m][n], 0, 0, 0);
#pragma unroll
      for (int n = 0; n < 2; ++n)
        acc[4][n] = __builtin_amdgcn_mfma_f32_16x16x32_bf16(ones, b[n], acc[4][n], 0, 0, 0);
    }
  }
  float* outp = kvp + ((size_t)bh * 8 + ls) * (65 * 128);
  const int colb = wave * 32 + fr;
#pragma unroll
  for (int n = 0; n < 2; ++n) {
    const int col = colb + n * 16;
#pragma unroll
    for (int m = 0; m < 4; ++m)
#pragma unroll
      for (int r = 0; r < 4; ++r)
        outp[(m * 16 + fq * 4 + r) * 128 + col] = acc[m][n][r];
    if (fq == 0) outp[64 * 128 + col] = acc[4][n][0];
  }
}

// ---------------- k3b: reduce partials -> kv_ext bf16 [bh][80][128] ----------------
__global__ __launch_bounds__(256) void kv_reduce(
    const float* __restrict__ kvp, unsigned short* __restrict__ kv_ext) {
  const int bh = blockIdx.x;
  for (int e = threadIdx.x; e < 80 * 128; e += 256) {
    const int row = e >> 7, c = e & 127;
    float v = 0.0f;
    if (row < 65) {
#pragma unroll
      for (int ls = 0; ls < 8; ++ls)
        v += kvp[((size_t)bh * 8 + ls) * (65 * 128) + row * 128 + c];
    }
    kv_ext[(size_t)bh * (80 * 128) + e] = f2bf(v);
  }
}

// ---------------- k4: attn = (q_ @ kv) / max(q_ . ksum, eps) ----------------
__global__ __launch_bounds__(256) void attn_phase2(
    const unsigned short* __restrict__ Qh, const unsigned short* __restrict__ kve,
    unsigned short* __restrict__ attn) {
  __shared__ unsigned short Qs[128 * 128];
  __shared__ unsigned short Ws[80 * 128];
  const int tid = threadIdx.x, wave = tid >> 6, lane = tid & 63;
  const int fr = lane & 15, fq = lane >> 4;
  const int l0 = blockIdx.x * 128;
  const int bh = blockIdx.y, b = bh >> 4, h = bh & 15;
#pragma unroll
  for (int j = 0; j < 5; ++j) {
    const int p = j * 256 + tid;
    const int r = p >> 4, scn = p & 15;
    const int cc = scn ^ (r & 7);
    GLD16(kve + ((size_t)bh * 80 + r) * 128 + cc * 8,
          Ws + ((size_t)(j * 256 + wave * 64)) * 8);
  }
#pragma unroll
  for (int it = 0; it < 4; ++it) {
    const int qc = it * 256 + tid;
    const int r = qc >> 3, dc = qc & 7;
    const uint4 w = *(const uint4*)(Qh + ((size_t)bh * 4096 + l0 + r) * 64 + dc * 8);
    float sv, cv;
    __sincosf(PI_F * (float)(l0 + r + 1) * (1.0f / 8192.0f), &sv, &cv);
    uint4 osn, ocs;
    osn.x = scale_pair(w.x, sv); osn.y = scale_pair(w.y, sv);
    osn.z = scale_pair(w.z, sv); osn.w = scale_pair(w.w, sv);
    ocs.x = scale_pair(w.x, cv); ocs.y = scale_pair(w.y, cv);
    ocs.z = scale_pair(w.z, cv); ocs.w = scale_pair(w.w, cv);
    const int ps = r * 16 + (dc ^ (r & 7));
    *(uint4*)&Qs[ps * 8] = osn;
    *(uint4*)&Qs[(ps + 8) * 8] = ocs;
  }
  __syncthreads();
  f32x4 acc[2][5] = {};
#pragma unroll
  for (int kk = 0; kk < 4; ++kk) {
    const int cc = kk * 4 + fq;
    bf16x8 a[2], bb[5];
#pragma unroll
    for (int m = 0; m < 2; ++m) {
      const int r = wave * 32 + m * 16 + fr;
      a[m] = *(const bf16x8*)&Qs[(r * 16 + (cc ^ (r & 7))) * 8];
    }
#pragma unroll
    for (int n = 0; n < 5; ++n) {
      const int r = n * 16 + fr;
      bb[n] = *(const bf16x8*)&Ws[(r * 16 + (cc ^ (r & 7))) * 8];
    }
#pragma unroll
    for (int m = 0; m < 2; ++m)
#pragma unroll
      for (int n = 0; n < 5; ++n)
        acc[m][n] = __builtin_amdgcn_mfma_f32_16x16x32_bf16(a[m], bb[n], acc[m][n], 0, 0, 0);
  }
#pragma unroll
  for (int m = 0; m < 2; ++m) {
#pragma unroll
    for (int r = 0; r < 4; ++r) {
      const float den = __shfl(acc[m][4][r], lane & 48);
      const float z = 1.0f / fmaxf(den, 1e-6f);
      const int l = l0 + wave * 32 + m * 16 + fq * 4 + r;
      const size_t ro = ((size_t)b * 4096 + l) * 1024 + (size_t)h * 64;
#pragma unroll
      for (int n = 0; n < 4; ++n)
        attn[ro + n * 16 + fr] = f2bf(acc[m][n][r] * z);
    }
  }
}

// ---------------- launch ----------------
extern "C" void kernel_launch(void* const* d_in, const int* in_sizes, int n_in,
                              void* d_out, int out_size, void* d_ws, size_t ws_size,
                              hipStream_t stream) {
  (void)in_sizes; (void)n_in; (void)out_size; (void)ws_size;
  const float* q  = (const float*)d_in[0];
  const float* k  = (const float*)d_in[1];
  const float* v  = (const float*)d_in[2];
  const float* Wq = (const float*)d_in[3];
  const float* bq = (const float*)d_in[4];
  const float* Wk = (const float*)d_in[5];
  const float* bk = (const float*)d_in[6];
  const float* Wv = (const float*)d_in[7];
  const float* bvp = (const float*)d_in[8];
  const float* Wo = (const float*)d_in[9];
  const float* bo = (const float*)d_in[10];

  char* ws = (char*)d_ws;
  unsigned short* Wqb = (unsigned short*)(ws + 0);
  unsigned short* Wkb = (unsigned short*)(ws + 2097152);
  unsigned short* Wvb = (unsigned short*)(ws + 4194304);
  unsigned short* Wob = (unsigned short*)(ws + 6291456);
  unsigned short* Qh  = (unsigned short*)(ws + 8388608);    // [bh][4096][64] bf16, 32 MB
  unsigned short* Vt  = (unsigned short*)(ws + 41943040);   // [bh][64][4096] bf16, 32 MB
  unsigned short* Kt  = (unsigned short*)(ws + 75497472);   // [bh][64][4096] bf16, 32 MB
  unsigned short* attnb = Kt;                               // alias: Kt dead after kv_gemm
  unsigned short* obf = Qh;                                 // alias: Qh dead after attn
  float* kvp          = (float*)(ws + 109051904);           // [512][65][128] f32
  unsigned short* kve = (unsigned short*)(ws + 126091264);  // [64][80][128] bf16

  convert_w<<<dim3(128, 4), 256, 0, stream>>>(Wq, Wk, Wv, Wo, Wqb, Wkb, Wvb, Wob);
  gemm_qkv<<<768, 512, 0, stream>>>(q, k, v, Wqb, Wkb, Wvb, bq, bk, bvp, Qh, Kt, Vt);
  kv_gemm<<<dim3(8, 64), 256, 0, stream>>>(Vt, Kt, kvp);
  kv_reduce<<<64, 256, 0, stream>>>(kvp, kve);
  attn_phase2<<<dim3(32, 64), 256, 0, stream>>>(Qh, kve, attnb);
  gemm_o<<<256, 512, 0, stream>>>(attnb, Wob, bo, obf);
  expand_bf16_f32<<<2048, 256, 0, stream>>>(obf, (float*)d_out);
}

// Round 21
// 225.723 us; speedup vs baseline: 1.0965x; 1.0965x over previous
//
#include <hip/hip_runtime.h>

typedef __bf16 bf16x8 __attribute__((ext_vector_type(8)));
typedef float f32x4 __attribute__((ext_vector_type(4)));

#define PI_F 3.14159265358979323846f

__device__ __forceinline__ unsigned short f2bf(float f) {
  unsigned u = __builtin_bit_cast(unsigned, f);
  u += 0x7fffu + ((u >> 16) & 1u);
  return (unsigned short)(u >> 16);
}

__device__ __forceinline__ unsigned scale_pair(unsigned w, float f) {
  const float lo = __builtin_bit_cast(float, w << 16);
  const float hi = __builtin_bit_cast(float, w & 0xffff0000u);
  return (unsigned)f2bf(lo * f) | ((unsigned)f2bf(hi * f) << 16);
}

#define GLD16(gp, lp)                                          \
  __builtin_amdgcn_global_load_lds(                            \
      (const __attribute__((address_space(1))) void*)(gp),     \
      (__attribute__((address_space(3))) void*)(lp), 16, 0, 0)

struct AReg { float4 a0, a1, a2, a3, a4, a5, a6, a7; };

__device__ __forceinline__ uint4 cvtpk16(float4 x, float4 y) {
  unsigned c0, c1, c2, c3;
  asm("v_cvt_pk_bf16_f32 %0, %1, %2" : "=v"(c0) : "v"(x.x), "v"(x.y));
  asm("v_cvt_pk_bf16_f32 %0, %1, %2" : "=v"(c1) : "v"(x.z), "v"(x.w));
  asm("v_cvt_pk_bf16_f32 %0, %1, %2" : "=v"(c2) : "v"(y.x), "v"(y.y));
  asm("v_cvt_pk_bf16_f32 %0, %1, %2" : "=v"(c3) : "v"(y.z), "v"(y.w));
  uint4 u; u.x = c0; u.y = c1; u.z = c2; u.w = c3;
  return u;
}

__device__ __forceinline__ uint2 cvtpk8(float a, float b, float c, float d) {
  unsigned lo, hi;
  asm("v_cvt_pk_bf16_f32 %0, %1, %2" : "=v"(lo) : "v"(a), "v"(b));
  asm("v_cvt_pk_bf16_f32 %0, %1, %2" : "=v"(hi) : "v"(c), "v"(d));
  uint2 r; r.x = lo; r.y = hi;
  return r;
}

__device__ __forceinline__ void unpack8(uint4 w, float* f) {
  f[0] = __builtin_bit_cast(float, w.x << 16);
  f[1] = __builtin_bit_cast(float, w.x & 0xffff0000u);
  f[2] = __builtin_bit_cast(float, w.y << 16);
  f[3] = __builtin_bit_cast(float, w.y & 0xffff0000u);
  f[4] = __builtin_bit_cast(float, w.z << 16);
  f[5] = __builtin_bit_cast(float, w.z & 0xffff0000u);
  f[6] = __builtin_bit_cast(float, w.w << 16);
  f[7] = __builtin_bit_cast(float, w.w & 0xffff0000u);
}

// ---------------- k1: weight fp32 -> bf16 conversion (weights only) ----------------
__global__ __launch_bounds__(256) void convert_w(
    const float* __restrict__ Wq, const float* __restrict__ Wk,
    const float* __restrict__ Wv, const float* __restrict__ Wo,
    unsigned short* __restrict__ Wqb, unsigned short* __restrict__ Wkb,
    unsigned short* __restrict__ Wvb, unsigned short* __restrict__ Wob) {
  const int region = blockIdx.y;
  const float* s; unsigned short* d;
  switch (region) {
    case 0: s = Wq; d = Wqb; break;
    case 1: s = Wk; d = Wkb; break;
    case 2: s = Wv; d = Wvb; break;
    default: s = Wo; d = Wob; break;
  }
  const float4* s4 = (const float4*)s;
  ushort4* d4 = (ushort4*)d;
  const int n4 = 262144;
  for (int i = blockIdx.x * 256 + threadIdx.x; i < n4; i += gridDim.x * 256) {
    float4 f = s4[i];
    ushort4 o;
    o.x = f2bf(f.x); o.y = f2bf(f.y); o.z = f2bf(f.z); o.w = f2bf(f.w);
    d4[i] = o;
  }
}

// ---------------- fused Q/K/V: 256x256 bf16 GEMM, 1-barrier/K-tile pipeline --------
// grid 768: seg = bid>>8 (0:Q relu->permuted Qh; 1:K relu->Kt; 2:V->Vt).
// LDS 160KB (A 2 bufs @0, B 3 bufs @32768), B staged 2 tiles ahead, single AReg.
// ONE barrier per K-tile: within-tile writes (AWRITE->abuf^1, BSTAGE->bbuf+2)
// never touch the buffers being read; AWRITE's implicit counted vmcnt on R
// guarantees B(kt+1) landed. lgkmcnt(0) before the barrier publishes ds_writes.
__global__ __launch_bounds__(512, 2) void gemm_qkv(
    const float* __restrict__ q, const float* __restrict__ k, const float* __restrict__ v,
    const unsigned short* __restrict__ Wqb, const unsigned short* __restrict__ Wkb,
    const unsigned short* __restrict__ Wvb,
    const float* __restrict__ bq, const float* __restrict__ bk, const float* __restrict__ bv,
    unsigned short* __restrict__ Qh, unsigned short* __restrict__ Kt,
    unsigned short* __restrict__ Vt) {
  constexpr int K = 1024, NKT = 16;
  __shared__ unsigned short S[81920];
  const int seg = blockIdx.x >> 8;
  const int bid2 = blockIdx.x & 255;
  const float* A32 = seg == 0 ? q : (seg == 1 ? k : v);
  const unsigned short* Bw = seg == 0 ? Wqb : (seg == 1 ? Wkb : Wvb);
  const float* bias = seg == 0 ? bq : (seg == 1 ? bk : bv);

  const int tid = threadIdx.x;
  const int wave = tid >> 6, lane = tid & 63;
  const int fr = lane & 15, fq = lane >> 4;
  const int wr = wave >> 2, wc = wave & 3;
  const int wg = (bid2 & 7) * 32 + (bid2 >> 3);
  const int mt = wg >> 2, ntile = wg & 3;
  const int m0 = mt * 256, n0 = ntile * 256;

  const int srow = tid >> 3;
  const int ac16 = tid & 7;
  const int scolE = ((ac16 << 4) ^ ((srow & 7) << 4)) >> 1;  // pre-swizzled src col (elems)
  const unsigned short* bSrc = Bw + (size_t)(n0 + srow) * K + scolE;
  const int awoff = (ac16 ^ (srow & 7)) << 3;  // swizzled dst chunk (elems)
  AReg R;

#define BSTAGE(kt_, idx_) do {                                                     \
    const int kc_ = (kt_) * 64;                                                    \
    unsigned short* bb_ = S + 32768 + (idx_) * 16384 + wave * 512;                 \
    GLD16(bSrc + kc_, bb_);                                                        \
    GLD16(bSrc + (size_t)65536 + kc_, bb_ + 4096);                                 \
    GLD16(bSrc + (size_t)131072 + kc_, bb_ + 8192);                                \
    GLD16(bSrc + (size_t)196608 + kc_, bb_ + 12288);                               \
  } while (0)

#define ALOAD_ALL(kt_) do {                                                        \
    const int kc_ = (kt_) * 64;                                                    \
    const float4* p_;                                                              \
    p_ = (const float4*)(A32 + (size_t)(m0 + srow) * K + kc_) + ac16 * 2;          \
    R.a0 = p_[0]; R.a1 = p_[1];                                                    \
    p_ = (const float4*)(A32 + (size_t)(m0 + 64 + srow) * K + kc_) + ac16 * 2;     \
    R.a2 = p_[0]; R.a3 = p_[1];                                                    \
    p_ = (const float4*)(A32 + (size_t)(m0 + 128 + srow) * K + kc_) + ac16 * 2;    \
    R.a4 = p_[0]; R.a5 = p_[1];                                                    \
    p_ = (const float4*)(A32 + (size_t)(m0 + 192 + srow) * K + kc_) + ac16 * 2;    \
    R.a6 = p_[0]; R.a7 = p_[1];                                                    \
  } while (0)

#define AWRITE_ALL(idx_) do {                                                      \
    unsigned short* dst_ = &S[(idx_) * 16384 + srow * 64 + awoff];                 \
    *(uint4*)(dst_)         = cvtpk16(R.a0, R.a1);                                 \
    *(uint4*)(dst_ + 4096)  = cvtpk16(R.a2, R.a3);                                 \
    *(uint4*)(dst_ + 8192)  = cvtpk16(R.a4, R.a5);                                 \
    *(uint4*)(dst_ + 12288) = cvtpk16(R.a6, R.a7);                                 \
  } while (0)

  const int xorv = (fr & 7) << 4;
  const unsigned cbE0 = (unsigned)(((fq * 16) ^ xorv) >> 1);
  const unsigned cbE1 = (unsigned)(((64 + fq * 16) ^ xorv) >> 1);

  f32x4 acc[8][4] = {};
  ALOAD_ALL(0);
  BSTAGE(0, 0);
  BSTAGE(1, 1);
  AWRITE_ALL(0);
  ALOAD_ALL(1);
  asm volatile("s_waitcnt vmcnt(12) lgkmcnt(0)" ::: "memory");
  __builtin_amdgcn_s_barrier();

  for (int kt = 0; kt < NKT; ++kt) {
    const unsigned aB = (unsigned)((kt & 1) * 16384 + wr * 8192 + fr * 64);
    int bcur = kt % 3;
    const unsigned bB = (unsigned)(32768 + bcur * 16384 + (wc >> 1) * 8192 +
                                   ((wc & 1) * 64 + fr) * 64);
    if (kt + 2 < NKT) {
      int bst = bcur + 2; if (bst >= 3) bst -= 3;
      BSTAGE(kt + 2, bst);
    }
    bf16x8 af[4][2], b0[2][2], b1[2][2];
    // ---- rows 0-63 of wave tile ----
#pragma unroll
    for (int mm = 0; mm < 4; ++mm) {
      const unsigned r = aB + (unsigned)(mm * 1024);
      af[mm][0] = *(const bf16x8*)&S[r + cbE0];
      af[mm][1] = *(const bf16x8*)&S[r + cbE1];
    }
#pragma unroll
    for (int nn = 0; nn < 2; ++nn) {
      const unsigned r0 = bB + (unsigned)(nn * 1024);
      b0[nn][0] = *(const bf16x8*)&S[r0 + cbE0];
      b0[nn][1] = *(const bf16x8*)&S[r0 + cbE1];
      const unsigned r1 = bB + (unsigned)((2 + nn) * 1024);
      b1[nn][0] = *(const bf16x8*)&S[r1 + cbE0];
      b1[nn][1] = *(const bf16x8*)&S[r1 + cbE1];
    }
    __builtin_amdgcn_s_setprio(1);
#pragma unroll
    for (int mm = 0; mm < 4; ++mm) {
#pragma unroll
      for (int nn = 0; nn < 2; ++nn) {
        acc[mm][nn] = __builtin_amdgcn_mfma_f32_16x16x32_bf16(af[mm][0], b0[nn][0], acc[mm][nn], 0, 0, 0);
        acc[mm][nn] = __builtin_amdgcn_mfma_f32_16x16x32_bf16(af[mm][1], b0[nn][1], acc[mm][nn], 0, 0, 0);
        acc[mm][2 + nn] = __builtin_amdgcn_mfma_f32_16x16x32_bf16(af[mm][0], b1[nn][0], acc[mm][2 + nn], 0, 0, 0);
        acc[mm][2 + nn] = __builtin_amdgcn_mfma_f32_16x16x32_bf16(af[mm][1], b1[nn][1], acc[mm][2 + nn], 0, 0, 0);
      }
    }
    __builtin_amdgcn_s_setprio(0);
    // ---- rows 64-127 of wave tile (same buffers; no barrier needed) ----
#pragma unroll
    for (int mm = 0; mm < 4; ++mm) {
      const unsigned r = aB + (unsigned)((4 + mm) * 1024);
      af[mm][0] = *(const bf16x8*)&S[r + cbE0];
      af[mm][1] = *(const bf16x8*)&S[r + cbE1];
    }
    if (kt + 1 < NKT) AWRITE_ALL((kt + 1) & 1);  // implicit counted vmcnt on R; covers B(kt+1)
    if (kt + 2 < NKT) ALOAD_ALL(kt + 2);
    __builtin_amdgcn_s_setprio(1);
#pragma unroll
    for (int mm = 0; mm < 4; ++mm) {
#pragma unroll
      for (int nn = 0; nn < 2; ++nn) {
        acc[4 + mm][nn] = __builtin_amdgcn_mfma_f32_16x16x32_bf16(af[mm][0], b0[nn][0], acc[4 + mm][nn], 0, 0, 0);
        acc[4 + mm][nn] = __builtin_amdgcn_mfma_f32_16x16x32_bf16(af[mm][1], b0[nn][1], acc[4 + mm][nn], 0, 0, 0);
        acc[4 + mm][2 + nn] = __builtin_amdgcn_mfma_f32_16x16x32_bf16(af[mm][0], b1[nn][0], acc[4 + mm][2 + nn], 0, 0, 0);
        acc[4 + mm][2 + nn] = __builtin_amdgcn_mfma_f32_16x16x32_bf16(af[mm][1], b1[nn][1], acc[4 + mm][2 + nn], 0, 0, 0);
      }
    }
    __builtin_amdgcn_s_setprio(0);
    asm volatile("s_waitcnt lgkmcnt(0)" ::: "memory");  // publish ds_writes
    __builtin_amdgcn_s_barrier();                        // single tile barrier
  }
#undef BSTAGE
#undef ALOAD_ALL
#undef AWRITE_ALL

  const int colb = n0 + wc * 64 + fr;
  const int rtb0 = wr * 128 + fq * 4;
  const int mlo = m0 & 4095;
  const int b16 = (m0 >> 12) << 4;
  const int hbase = n0 >> 6;

  if (seg == 0) {
    // Q: relu -> LDS row-major [rt:256][ct:256] (16B-chunk swizzled) -> 128B runs
    float bb4[4];
#pragma unroll
    for (int nq = 0; nq < 4; ++nq) bb4[nq] = bias[colb + nq * 16];
    __syncthreads();
#pragma unroll
    for (int mq = 0; mq < 8; ++mq) {
#pragma unroll
      for (int rr = 0; rr < 4; ++rr) {
        const int rt = rtb0 + mq * 16 + rr;
        const int e = (rt >> 2) & 7;
#pragma unroll
        for (int nq = 0; nq < 4; ++nq) {
          const int ct = wc * 64 + nq * 16 + fr;
          const int sct = (ct & 7) | ((((ct >> 3) ^ e) & 31) << 3);
          S[rt * 256 + sct] = f2bf(fmaxf(acc[mq][nq][rr] + bb4[nq], 0.0f));
        }
      }
    }
    __syncthreads();
#pragma unroll
    for (int it = 0; it < 16; ++it) {
      const int rt = it * 16 + (tid >> 5);
      const int co = tid & 31;
      const int chunk = co ^ ((rt >> 2) & 7);
      uint4 w = *(const uint4*)&S[rt * 256 + chunk * 8];
      const int h = hbase + (co >> 3);
      const size_t addr = ((size_t)(b16 + h) * 4096 + mlo + rt) * 64 + ((co & 7) << 3);
      *(uint4*)(Qh + addr) = w;
    }
  } else {
    // K/V: transposed [bh][64][4096] bf16 via LDS col-major transpose; relu iff K
    const bool relu = (seg == 1);
    unsigned short* G = relu ? Kt : Vt;
    float bb4[4];
#pragma unroll
    for (int nq = 0; nq < 4; ++nq) bb4[nq] = bias[colb + nq * 16];
#pragma unroll
    for (int mq = 0; mq < 8; ++mq)
#pragma unroll
      for (int nq = 0; nq < 4; ++nq)
#pragma unroll
        for (int rr = 0; rr < 4; ++rr) {
          float val = acc[mq][nq][rr] + bb4[nq];
          if (relu) val = fmaxf(val, 0.0f);
          acc[mq][nq][rr] = val;
        }
    __syncthreads();
#pragma unroll
    for (int mq = 0; mq < 8; ++mq) {
      const int rtb = rtb0 + mq * 16;
#pragma unroll
      for (int nq = 0; nq < 4; ++nq) {
        const int ct = wc * 64 + nq * 16 + fr;
        uint2 w = cvtpk8(acc[mq][nq][0], acc[mq][nq][1], acc[mq][nq][2], acc[mq][nq][3]);
        *(uint2*)&S[ct * 256 + (rtb ^ ((ct & 7) << 2))] = w;
      }
    }
    __syncthreads();
#pragma unroll
    for (int it = 0; it < 16; ++it) {
      const int ct = it * 16 + (tid >> 5);
      const int lo = (tid & 31) << 3;
      const int sw = (ct & 7) << 2;
      uint2 r0 = *(const uint2*)&S[ct * 256 + (lo ^ sw)];
      uint2 r1 = *(const uint2*)&S[ct * 256 + ((lo + 4) ^ sw)];
      uint4 w; w.x = r0.x; w.y = r0.y; w.z = r1.x; w.w = r1.y;
      const int h = hbase + (ct >> 6), dd = ct & 63;
      const size_t addr = ((size_t)(b16 + h) * 64 + dd) * 4096 + mlo + lo;
      *(uint4*)(G + addr) = w;
    }
  }
}

// ---------------- O projection: 1-barrier/K-tile, bf16 A, bf16 out ----------------
__global__ __launch_bounds__(512, 2) void gemm_o(
    const unsigned short* __restrict__ Ain, const unsigned short* __restrict__ Bw,
    const float* __restrict__ bias, unsigned short* __restrict__ out) {
  constexpr int K = 1024, NKT = 16;
  __shared__ unsigned short S[81920];  // A 2 bufs @0, B 3 bufs @32768
  const int tid = threadIdx.x;
  const int wave = tid >> 6, lane = tid & 63;
  const int fr = lane & 15, fq = lane >> 4;
  const int wr = wave >> 2, wc = wave & 3;
  const int wg = (blockIdx.x & 7) * 32 + (blockIdx.x >> 3);
  const int mt = wg >> 2, ntile = wg & 3;
  const int m0 = mt * 256, n0 = ntile * 256;

  const int srow = tid >> 3;
  const int ac16 = tid & 7;
  const int scolE = ((ac16 << 4) ^ ((srow & 7) << 4)) >> 1;
  const unsigned short* bSrc = Bw + (size_t)(n0 + srow) * K + scolE;
  const unsigned short* aSrcB = Ain + (size_t)(m0 + srow) * K + scolE;

#define BSTAGE(kt_, idx_) do {                                                     \
    const int kc_ = (kt_) * 64;                                                    \
    unsigned short* bb_ = S + 32768 + (idx_) * 16384 + wave * 512;                 \
    GLD16(bSrc + kc_, bb_);                                                        \
    GLD16(bSrc + (size_t)65536 + kc_, bb_ + 4096);                                 \
    GLD16(bSrc + (size_t)131072 + kc_, bb_ + 8192);                                \
    GLD16(bSrc + (size_t)196608 + kc_, bb_ + 12288);                               \
  } while (0)

#define ASTAGE(kt_, idx_) do {                                                     \
    const int kc_ = (kt_) * 64;                                                    \
    unsigned short* ab_ = S + (idx_) * 16384 + wave * 512;                         \
    GLD16(aSrcB + kc_, ab_);                                                       \
    GLD16(aSrcB + (size_t)65536 + kc_, ab_ + 4096);                                \
    GLD16(aSrcB + (size_t)131072 + kc_, ab_ + 8192);                               \
    GLD16(aSrcB + (size_t)196608 + kc_, ab_ + 12288);                              \
  } while (0)

  const int xorv = (fr & 7) << 4;
  const unsigned cbE0 = (unsigned)(((fq * 16) ^ xorv) >> 1);
  const unsigned cbE1 = (unsigned)(((64 + fq * 16) ^ xorv) >> 1);

  f32x4 acc[8][4] = {};
  ASTAGE(0, 0);
  BSTAGE(0, 0);
  BSTAGE(1, 1);
  asm volatile("s_waitcnt vmcnt(4)" ::: "memory");
  __builtin_amdgcn_s_barrier();

  int bcur = 0;
  for (int kt = 0; kt < NKT; ++kt) {
    const unsigned aB = (unsigned)((kt & 1) * 16384 + wr * 8192 + fr * 64);
    const unsigned bB = (unsigned)(32768 + bcur * 16384 + (wc >> 1) * 8192 +
                                   ((wc & 1) * 64 + fr) * 64);
    if (kt + 2 < NKT) {
      int bst = bcur + 2; if (bst >= 3) bst -= 3;
      BSTAGE(kt + 2, bst);
    }
    if (kt + 1 < NKT) ASTAGE(kt + 1, (kt + 1) & 1);
    bf16x8 af[4][2], b0[2][2], b1[2][2];
#pragma unroll
    for (int mm = 0; mm < 4; ++mm) {
      const unsigned r = aB + (unsigned)(mm * 1024);
      af[mm][0] = *(const bf16x8*)&S[r + cbE0];
      af[mm][1] = *(const bf16x8*)&S[r + cbE1];
    }
#pragma unroll
    for (int nn = 0; nn < 2; ++nn) {
      const unsigned r0 = bB + (unsigned)(nn * 1024);
      b0[nn][0] = *(const bf16x8*)&S[r0 + cbE0];
      b0[nn][1] = *(const bf16x8*)&S[r0 + cbE1];
      const unsigned r1 = bB + (unsigned)((2 + nn) * 1024);
      b1[nn][0] = *(const bf16x8*)&S[r1 + cbE0];
      b1[nn][1] = *(const bf16x8*)&S[r1 + cbE1];
    }
    __builtin_amdgcn_s_setprio(1);
#pragma unroll
    for (int mm = 0; mm < 4; ++mm) {
#pragma unroll
      for (int nn = 0; nn < 2; ++nn) {
        acc[mm][nn] = __builtin_amdgcn_mfma_f32_16x16x32_bf16(af[mm][0], b0[nn][0], acc[mm][nn], 0, 0, 0);
        acc[mm][nn] = __builtin_amdgcn_mfma_f32_16x16x32_bf16(af[mm][1], b0[nn][1], acc[mm][nn], 0, 0, 0);
        acc[mm][2 + nn] = __builtin_amdgcn_mfma_f32_16x16x32_bf16(af[mm][0], b1[nn][0], acc[mm][2 + nn], 0, 0, 0);
        acc[mm][2 + nn] = __builtin_amdgcn_mfma_f32_16x16x32_bf16(af[mm][1], b1[nn][1], acc[mm][2 + nn], 0, 0, 0);
      }
    }
    __builtin_amdgcn_s_setprio(0);
#pragma unroll
    for (int mm = 0; mm < 4; ++mm) {
      const unsigned r = aB + (unsigned)((4 + mm) * 1024);
      af[mm][0] = *(const bf16x8*)&S[r + cbE0];
      af[mm][1] = *(const bf16x8*)&S[r + cbE1];
    }
    __builtin_amdgcn_s_setprio(1);
#pragma unroll
    for (int mm = 0; mm < 4; ++mm) {
#pragma unroll
      for (int nn = 0; nn < 2; ++nn) {
        acc[4 + mm][nn] = __builtin_amdgcn_mfma_f32_16x16x32_bf16(af[mm][0], b0[nn][0], acc[4 + mm][nn], 0, 0, 0);
        acc[4 + mm][nn] = __builtin_amdgcn_mfma_f32_16x16x32_bf16(af[mm][1], b0[nn][1], acc[4 + mm][nn], 0, 0, 0);
        acc[4 + mm][2 + nn] = __builtin_amdgcn_mfma_f32_16x16x32_bf16(af[mm][0], b1[nn][0], acc[4 + mm][2 + nn], 0, 0, 0);
        acc[4 + mm][2 + nn] = __builtin_amdgcn_mfma_f32_16x16x32_bf16(af[mm][1], b1[nn][1], acc[4 + mm][2 + nn], 0, 0, 0);
      }
    }
    __builtin_amdgcn_s_setprio(0);
    // counted wait: A(kt+1), B(kt+1) landed; only B(kt+2)'s 4 loads newer
    if (kt + 2 < NKT) {
      asm volatile("s_waitcnt vmcnt(4) lgkmcnt(0)" ::: "memory");
    } else if (kt + 1 < NKT) {
      asm volatile("s_waitcnt vmcnt(0) lgkmcnt(0)" ::: "memory");
    } else {
      asm volatile("s_waitcnt lgkmcnt(0)" ::: "memory");
    }
    __builtin_amdgcn_s_barrier();
    bcur = bcur + 1; if (bcur == 3) bcur = 0;
  }
#undef BSTAGE
#undef ASTAGE

  // bf16 row-major out via 4-pass LDS row gather; 512B runs per wave-store.
  const int colb = n0 + wc * 64 + fr;
  float* Sf = (float*)S;  // 64 rows x 260 f32
  float bb4[4];
#pragma unroll
  for (int nq = 0; nq < 4; ++nq) bb4[nq] = bias[colb + nq * 16];
  const int colL = wc * 64;
#pragma unroll
  for (int h4 = 0; h4 < 4; ++h4) {
    __syncthreads();
    if (wr == (h4 >> 1)) {
      const int mqb = (h4 & 1) * 4;
#pragma unroll
      for (int mq2 = 0; mq2 < 4; ++mq2) {
        const int rl = mq2 * 16 + fq * 4;
#pragma unroll
        for (int nq = 0; nq < 4; ++nq) {
#pragma unroll
          for (int rr = 0; rr < 4; ++rr)
            Sf[(rl + rr) * 260 + colL + nq * 16 + fr] = acc[mqb + mq2][nq][rr] + bb4[nq];
        }
      }
    }
    __syncthreads();
#pragma unroll
    for (int i = 0; i < 8; ++i) {
      const int rl = wave * 8 + i;
      const int gr = m0 + h4 * 64 + rl;
      f32x4 v4 = *(const f32x4*)&Sf[rl * 260 + lane * 4];
      uint2 w = cvtpk8(v4.x, v4.y, v4.z, v4.w);
      *(uint2*)(out + (size_t)gr * 1024 + n0 + lane * 4) = w;
    }
  }
}

// ---------------- expand: bf16 [16384][1024] -> fp32 d_out (fully coalesced) ------
__global__ __launch_bounds__(256) void expand_bf16_f32(
    const unsigned short* __restrict__ in, float* __restrict__ out) {
  const int stride = gridDim.x * 256;
  for (int i = blockIdx.x * 256 + threadIdx.x; i < 4194304; i += stride) {
    uint2 w = ((const uint2*)in)[i];
    f32x4 o;
    o.x = __builtin_bit_cast(float, w.x << 16);
    o.y = __builtin_bit_cast(float, w.x & 0xffff0000u);
    o.z = __builtin_bit_cast(float, w.y << 16);
    o.w = __builtin_bit_cast(float, w.y & 0xffff0000u);
    ((f32x4*)out)[i] = o;
  }
}

// ---------------- k3: kv partial GEMM via MFMA, sin/cos expansion in-kernel ----------------
__global__ __launch_bounds__(256, 2) void kv_gemm(
    const unsigned short* __restrict__ Vt,   // [64][64][4096]
    const unsigned short* __restrict__ Kt,   // [64][64][4096], relu'd
    float* __restrict__ kvp) {               // [64*8][65][128]
  __shared__ unsigned short As[64 * 64];
  __shared__ unsigned short Bs[128 * 64];
  __shared__ float sn[512], cn[512];
  const int tid = threadIdx.x, wave = tid >> 6, lane = tid & 63;
  const int fr = lane & 15, fq = lane >> 4;
  const int ls = blockIdx.x, bh = blockIdx.y;
  const size_t base = (size_t)bh * 64 * 4096;
  {
    float s0, c0, s1, c1;
    __sincosf(PI_F * (float)(ls * 512 + tid + 1) * (1.0f / 8192.0f), &s0, &c0);
    __sincosf(PI_F * (float)(ls * 512 + tid + 257) * (1.0f / 8192.0f), &s1, &c1);
    sn[tid] = s0; cn[tid] = c0;
    sn[tid + 256] = s1; cn[tid + 256] = c1;
  }
  f32x4 acc[5][2] = {};
  bf16x8 ones;
#pragma unroll
  for (int j = 0; j < 8; ++j) ones[j] = (__bf16)1.0f;
  for (int t = 0; t < 8; ++t) {
    const int l0 = ls * 512 + t * 64;
    __syncthreads();
#pragma unroll
    for (int j = 0; j < 2; ++j) {
      const int p = j * 256 + tid;
      const int row = p >> 3, cc = (p & 7) ^ (row & 7);
      GLD16(Vt + base + (size_t)row * 4096 + l0 + cc * 8,
            As + ((j << 8) + (wave << 6)) * 8);
    }
#pragma unroll
    for (int j = 0; j < 2; ++j) {
      const int p = j * 256 + tid;
      const int kr = p >> 3, cc = p & 7;
      const uint4 w = *(const uint4*)(Kt + base + (size_t)kr * 4096 + l0 + cc * 8);
      const int tl = t * 64 + cc * 8;
      float kf[8];
      unpack8(w, kf);
      const float4 sA = *(const float4*)&sn[tl], sB = *(const float4*)&sn[tl + 4];
      const float4 cA = *(const float4*)&cn[tl], cB = *(const float4*)&cn[tl + 4];
      float4 x0, x1;
      x0.x = kf[0] * sA.x; x0.y = kf[1] * sA.y; x0.z = kf[2] * sA.z; x0.w = kf[3] * sA.w;
      x1.x = kf[4] * sB.x; x1.y = kf[5] * sB.y; x1.z = kf[6] * sB.z; x1.w = kf[7] * sB.w;
      const uint4 wsn = cvtpk16(x0, x1);
      x0.x = kf[0] * cA.x; x0.y = kf[1] * cA.y; x0.z = kf[2] * cA.z; x0.w = kf[3] * cA.w;
      x1.x = kf[4] * cB.x; x1.y = kf[5] * cB.y; x1.z = kf[6] * cB.z; x1.w = kf[7] * cB.w;
      const uint4 wcn = cvtpk16(x0, x1);
      const int sw_ = cc ^ (kr & 7);
      *(uint4*)&Bs[(kr * 8 + sw_) * 8] = wsn;
      *(uint4*)&Bs[((kr + 64) * 8 + sw_) * 8] = wcn;
    }
    __syncthreads();
#pragma unroll
    for (int kk = 0; kk < 2; ++kk) {
      const int ch = kk * 4 + fq;
      bf16x8 a[4], b[2];
#pragma unroll
      for (int m = 0; m < 4; ++m) {
        const int r = m * 16 + fr;
        a[m] = *(const bf16x8*)&As[(r * 8 + (ch ^ (r & 7))) * 8];
      }
#pragma unroll
      for (int n = 0; n < 2; ++n) {
        const int r = wave * 32 + n * 16 + fr;
        b[n] = *(const bf16x8*)&Bs[(r * 8 + (ch ^ (r & 7))) * 8];
      }
#pragma unroll
      for (int m = 0; m < 4; ++m)
#pragma unroll
        for (int n = 0; n < 2; ++n)
          acc[m][n] = __builtin_amdgcn_mfma_f32_16x16x32_bf16(a[m], b[n], acc[m][n], 0, 0, 0);
#pragma unroll
      for (int n = 0; n < 2; ++n)
        acc[4][n] = __builtin_amdgcn_mfma_f32_16x16x32_bf16(ones, b[n], acc[4][n], 0, 0, 0);
    }
  }
  float* outp = kvp + ((size_t)bh * 8 + ls) * (65 * 128);
  const int colb = wave * 32 + fr;
#pragma unroll
  for (int n = 0; n < 2; ++n) {
    const int col = colb + n * 16;
#pragma unroll
    for (int m = 0; m < 4; ++m)
#pragma unroll
      for (int r = 0; r < 4; ++r)
        outp[(m * 16 + fq * 4 + r) * 128 + col] = acc[m][n][r];
    if (fq == 0) outp[64 * 128 + col] = acc[4][n][0];
  }
}

// ---------------- k3b: reduce partials -> kv_ext bf16 [bh][80][128] ----------------
__global__ __launch_bounds__(256) void kv_reduce(
    const float* __restrict__ kvp, unsigned short* __restrict__ kv_ext) {
  const int bh = blockIdx.x;
  for (int e = threadIdx.x; e < 80 * 128; e += 256) {
    const int row = e >> 7, c = e & 127;
    float v = 0.0f;
    if (row < 65) {
#pragma unroll
      for (int ls = 0; ls < 8; ++ls)
        v += kvp[((size_t)bh * 8 + ls) * (65 * 128) + row * 128 + c];
    }
    kv_ext[(size_t)bh * (80 * 128) + e] = f2bf(v);
  }
}

// ---------------- k4: attn = (q_ @ kv) / max(q_ . ksum, eps) ----------------
__global__ __launch_bounds__(256) void attn_phase2(
    const unsigned short* __restrict__ Qh, const unsigned short* __restrict__ kve,
    unsigned short* __restrict__ attn) {
  __shared__ unsigned short Qs[128 * 128];
  __shared__ unsigned short Ws[80 * 128];
  const int tid = threadIdx.x, wave = tid >> 6, lane = tid & 63;
  const int fr = lane & 15, fq = lane >> 4;
  const int l0 = blockIdx.x * 128;
  const int bh = blockIdx.y, b = bh >> 4, h = bh & 15;
#pragma unroll
  for (int j = 0; j < 5; ++j) {
    const int p = j * 256 + tid;
    const int r = p >> 4, scn = p & 15;
    const int cc = scn ^ (r & 7);
    GLD16(kve + ((size_t)bh * 80 + r) * 128 + cc * 8,
          Ws + ((size_t)(j * 256 + wave * 64)) * 8);
  }
#pragma unroll
  for (int it = 0; it < 4; ++it) {
    const int qc = it * 256 + tid;
    const int r = qc >> 3, dc = qc & 7;
    const uint4 w = *(const uint4*)(Qh + ((size_t)bh * 4096 + l0 + r) * 64 + dc * 8);
    float sv, cv;
    __sincosf(PI_F * (float)(l0 + r + 1) * (1.0f / 8192.0f), &sv, &cv);
    uint4 osn, ocs;
    osn.x = scale_pair(w.x, sv); osn.y = scale_pair(w.y, sv);
    osn.z = scale_pair(w.z, sv); osn.w = scale_pair(w.w, sv);
    ocs.x = scale_pair(w.x, cv); ocs.y = scale_pair(w.y, cv);
    ocs.z = scale_pair(w.z, cv); ocs.w = scale_pair(w.w, cv);
    const int ps = r * 16 + (dc ^ (r & 7));
    *(uint4*)&Qs[ps * 8] = osn;
    *(uint4*)&Qs[(ps + 8) * 8] = ocs;
  }
  __syncthreads();
  f32x4 acc[2][5] = {};
#pragma unroll
  for (int kk = 0; kk < 4; ++kk) {
    const int cc = kk * 4 + fq;
    bf16x8 a[2], bb[5];
#pragma unroll
    for (int m = 0; m < 2; ++m) {
      const int r = wave * 32 + m * 16 + fr;
      a[m] = *(const bf16x8*)&Qs[(r * 16 + (cc ^ (r & 7))) * 8];
    }
#pragma unroll
    for (int n = 0; n < 5; ++n) {
      const int r = n * 16 + fr;
      bb[n] = *(const bf16x8*)&Ws[(r * 16 + (cc ^ (r & 7))) * 8];
    }
#pragma unroll
    for (int m = 0; m < 2; ++m)
#pragma unroll
      for (int n = 0; n < 5; ++n)
        acc[m][n] = __builtin_amdgcn_mfma_f32_16x16x32_bf16(a[m], bb[n], acc[m][n], 0, 0, 0);
  }
#pragma unroll
  for (int m = 0; m < 2; ++m) {
#pragma unroll
    for (int r = 0; r < 4; ++r) {
      const float den = __shfl(acc[m][4][r], lane & 48);
      const float z = 1.0f / fmaxf(den, 1e-6f);
      const int l = l0 + wave * 32 + m * 16 + fq * 4 + r;
      const size_t ro = ((size_t)b * 4096 + l) * 1024 + (size_t)h * 64;
#pragma unroll
      for (int n = 0; n < 4; ++n)
        attn[ro + n * 16 + fr] = f2bf(acc[m][n][r] * z);
    }
  }
}

// ---------------- launch ----------------
extern "C" void kernel_launch(void* const* d_in, const int* in_sizes, int n_in,
                              void* d_out, int out_size, void* d_ws, size_t ws_size,
                              hipStream_t stream) {
  (void)in_sizes; (void)n_in; (void)out_size; (void)ws_size;
  const float* q  = (const float*)d_in[0];
  const float* k  = (const float*)d_in[1];
  const float* v  = (const float*)d_in[2];
  const float* Wq = (const float*)d_in[3];
  const float* bq = (const float*)d_in[4];
  const float* Wk = (const float*)d_in[5];
  const float* bk = (const float*)d_in[6];
  const float* Wv = (const float*)d_in[7];
  const float* bvp = (const float*)d_in[8];
  const float* Wo = (const float*)d_in[9];
  const float* bo = (const float*)d_in[10];

  char* ws = (char*)d_ws;
  unsigned short* Wqb = (unsigned short*)(ws + 0);
  unsigned short* Wkb = (unsigned short*)(ws + 2097152);
  unsigned short* Wvb = (unsigned short*)(ws + 4194304);
  unsigned short* Wob = (unsigned short*)(ws + 6291456);
  unsigned short* Qh  = (unsigned short*)(ws + 8388608);    // [bh][4096][64] bf16, 32 MB
  unsigned short* Vt  = (unsigned short*)(ws + 41943040);   // [bh][64][4096] bf16, 32 MB
  unsigned short* Kt  = (unsigned short*)(ws + 75497472);   // [bh][64][4096] bf16, 32 MB
  unsigned short* attnb = Kt;                               // alias: Kt dead after kv_gemm
  unsigned short* obf = Qh;                                 // alias: Qh dead after attn
  float* kvp          = (float*)(ws + 109051904);           // [512][65][128] f32
  unsigned short* kve = (unsigned short*)(ws + 126091264);  // [64][80][128] bf16

  convert_w<<<dim3(128, 4), 256, 0, stream>>>(Wq, Wk, Wv, Wo, Wqb, Wkb, Wvb, Wob);
  gemm_qkv<<<768, 512, 0, stream>>>(q, k, v, Wqb, Wkb, Wvb, bq, bk, bvp, Qh, Kt, Vt);
  kv_gemm<<<dim3(8, 64), 256, 0, stream>>>(Vt, Kt, kvp);
  kv_reduce<<<64, 256, 0, stream>>>(kvp, kve);
  attn_phase2<<<dim3(32, 64), 256, 0, stream>>>(Qh, kve, attnb);
  gemm_o<<<256, 512, 0, stream>>>(attnb, Wob, bo, obf);
  expand_bf16_f32<<<2048, 256, 0, stream>>>(obf, (float*)d_out);
}